// Round 2
// baseline (1784.463 us; speedup 1.0000x reference)
//
#include <hip/hip_runtime.h>
#include <math.h>

#define DD 33
#define TT 49
#define HH 64
#define NB 33
#define NT 256

// ws layout (float offsets)
#define O_WIHT   0        // 33*192  gru_wih^T
#define O_WHHT   6336     // 64*192  gru_whh^T
#define O_WU0T   18624    // 64*64   wu0_w^T
#define O_WU1T   22720    // 128*64  wu1_w^T
#define O_WUT    30912    // 192*64  wu_w^T
#define O_GH     43200    // 49*64   gamma_h[t][i]
#define O_GS     46336    // 49*64   gamma_st[t][i]
#define O_XC     49472    // 49*33   published x_st_c
#define O_R      51089    // 49*66   published r1(33), r2(33)
#define CTR_OFF  54324    // unsigned arrival counter (own cache line)
#define FLAG_OFF (CTR_OFF + 64)  // broadcast flag, separate 256B line
#define PREP_N   49472

#define SC_AGENT __HIP_MEMORY_SCOPE_AGENT

__device__ __forceinline__ float sigm(float x) { return 1.f / (1.f + expf(-x)); }

__device__ __forceinline__ float rsum64(float v) {
#pragma unroll
  for (int o = 32; o > 0; o >>= 1) v += __shfl_xor(v, o, 64);
  return v;
}
__device__ __forceinline__ float rmax64(float v) {
#pragma unroll
  for (int o = 32; o > 0; o >>= 1) v = fmaxf(v, __shfl_xor(v, o, 64));
  return v;
}

extern "C" __global__ void gmgru_prep(
    const float* __restrict__ data, const float* __restrict__ gh_w,
    const float* __restrict__ gh_b, const float* __restrict__ gst_w,
    const float* __restrict__ gst_b, const float* __restrict__ wih,
    const float* __restrict__ whh, const float* __restrict__ wu0,
    const float* __restrict__ wu1, const float* __restrict__ wu,
    float* __restrict__ ws) {
  int idx = blockIdx.x * blockDim.x + threadIdx.x;
  if (idx < 6336) {                       // wihT[k*192+j] = wih[j*33+k]
    int k = idx / 192, j = idx % 192;
    ws[O_WIHT + idx] = wih[j * DD + k];
  } else if (idx < 18624) {               // whhT[k*192+j] = whh[j*64+k]
    int r = idx - 6336; int k = r / 192, j = r % 192;
    ws[O_WHHT + r] = whh[j * HH + k];
  } else if (idx < 22720) {               // wu0T[k*64+q] = wu0[q*64+k]
    int r = idx - 18624; int k = r / 64, q = r % 64;
    ws[O_WU0T + r] = wu0[q * HH + k];
  } else if (idx < 30912) {               // wu1T[k*64+q] = wu1[q*128+k]
    int r = idx - 22720; int k = r / 64, q = r % 64;
    ws[O_WU1T + r] = wu1[q * 128 + k];
  } else if (idx < 43200) {               // wuT[k*64+q] = wu[q*192+k]
    int r = idx - 30912; int k = r / 64, q = r % 64;
    ws[O_WUT + r] = wu[q * 192 + k];
  } else if (idx < 46336) {               // gamma_h[t][i]
    int r = idx - 43200; int t = r / 64, i = r % 64;
    float s = gh_b[i];
    for (int d2 = 0; d2 < DD; ++d2)
      s += data[2 * DD * TT + d2 * TT + t] * gh_w[i * DD + d2];
    ws[O_GH + r] = expf(-fmaxf(s, 0.f));
  } else if (idx < PREP_N) {              // gamma_st[t][i]
    int r = idx - 46336; int t = r / 64, i = r % 64;
    float s = gst_b[i];
    for (int d2 = 0; d2 < DD; ++d2)
      s += data[2 * DD * TT + d2 * TT + t] * gst_w[i * DD + d2];
    ws[O_GS + r] = expf(-fmaxf(s, 0.f));
  }
}

// u_t partial: acc += ws[OFS + k*64 + q] * HARR[k], k=0..63, 4-way ILP
#define DOT64(OFS, HARR, ACC)                                     \
  {                                                               \
    float a0 = 0.f, a1 = 0.f, a2 = 0.f, a3 = 0.f;                 \
    _Pragma("unroll") for (int k = 0; k < HH; k += 4) {           \
      a0 += ws[(OFS) + (k + 0) * 64 + q] * (HARR)[k + 0];         \
      a1 += ws[(OFS) + (k + 1) * 64 + q] * (HARR)[k + 1];         \
      a2 += ws[(OFS) + (k + 2) * 64 + q] * (HARR)[k + 2];         \
      a3 += ws[(OFS) + (k + 3) * 64 + q] * (HARR)[k + 3];         \
    }                                                             \
    ACC += ((a0 + a1) + (a2 + a3));                               \
  }

extern "C" __global__ void __launch_bounds__(NT, 1)
gmgru_main(const float* __restrict__ data, const float* __restrict__ h0,
           const float* __restrict__ H0, const float* __restrict__ bih,
           const float* __restrict__ bhh, const float* __restrict__ wu0b,
           const float* __restrict__ wu1b, const float* __restrict__ wub,
           const float* __restrict__ wh_w, const float* __restrict__ wh_b,
           const float* __restrict__ xst_w, const float* __restrict__ xst_b,
           const float* __restrict__ wrg_w, const float* __restrict__ wrs,
           const float* __restrict__ tWz, const float* __restrict__ tUzx,
           const float* __restrict__ tUzh, const float* __restrict__ tWr,
           const float* __restrict__ tUrx, const float* __restrict__ tUrh,
           const float* __restrict__ tWh, const float* __restrict__ tUhx,
           const float* __restrict__ tUhh, const float* __restrict__ tbz,
           const float* __restrict__ tbr, const float* __restrict__ tbh,
           float* __restrict__ ws, unsigned* __restrict__ cnt,
           unsigned* __restrict__ flagp, float* __restrict__ out) {
  __shared__ __attribute__((aligned(16))) float wbuf[6][4096];  // 96 KB
  __shared__ float wihT_l[6336];                                // 25 KB
  __shared__ float ux[3][HH], tb[3][HH];
  __shared__ float Hrow[HH], Hdec[HH], hpre[HH], hprev[HH], hnew_l[HH], h0s[HH];
  __shared__ float hist[3][HH];
  __shared__ float ghL[3 * HH];
  __shared__ float uvec[HH];
  __shared__ float part[4][4][HH];
  __shared__ float bihL[3 * HH], bhhL[3 * HH];
  __shared__ float whr0[HH], whr1[HH], wrgr[HH], wrsr[HH], xstwL[HH];
  __shared__ float xrow[TT], mrow[TT];
  __shared__ float gpre[2][HH];   // prefetched gamma for current step
  __shared__ float scal2[2][2];   // [t&1][0]=xgt+b, [1]=x_st

  const int tid = threadIdx.x;
  const int dd = blockIdx.x;
  const int wid = tid >> 6;
  const int lane = tid & 63;

  // ---- one-time staging ----
  {
    const float* srcs[6] = {tWz, tUzh, tWr, tUrh, tWh, tUhh};
#pragma unroll
    for (int m = 0; m < 6; ++m) {
      const float* s = srcs[m] + dd * 4096;
#pragma unroll
      for (int c = 0; c < 4; ++c) {
        int f = tid * 16 + c * 4;                 // source flat idx (i*64+k)
        float4 v = *reinterpret_cast<const float4*>(s + f);
        int i = f >> 6, k = f & 63;
        *reinterpret_cast<float4*>(&wbuf[m][(k >> 2) * 256 + i * 4]) = v;
      }
    }
  }
  for (int i = tid; i < 6336; i += NT) wihT_l[i] = ws[O_WIHT + i];
  for (int i = tid; i < 3 * HH; i += NT) { bihL[i] = bih[i]; bhhL[i] = bhh[i]; }
  if (tid < HH) {
    ux[0][tid] = tUzx[dd * HH + tid];
    ux[1][tid] = tUrx[dd * HH + tid];
    ux[2][tid] = tUhx[dd * HH + tid];
    tb[0][tid] = tbz[tid];
    tb[1][tid] = tbr[tid];
    tb[2][tid] = tbh[tid];
    Hrow[tid] = H0[dd * HH + tid];
    float h0v = h0[tid];
    h0s[tid] = h0v;
    hprev[tid] = h0v;
    whr0[tid] = wh_w[dd * 128 + tid];
    whr1[tid] = wh_w[dd * 128 + 64 + tid];
    wrgr[tid] = wrg_w[dd * HH + tid];
    wrsr[tid] = wrs[tid];
    xstwL[tid] = xst_w[tid];
    gpre[0][tid] = ws[O_GH + tid];
    gpre[1][tid] = ws[O_GS + tid];
  }
  if (tid < TT) {
    xrow[tid] = data[dd * TT + tid];
    mrow[tid] = data[DD * TT + dd * TT + tid];
  }
  __syncthreads();

  float xst_cur = 0.f;  // wave0 lane0 only
  // ---- prologue: publish xc[0], arrive round 0 ----
  if (wid == 0) {
    float s = rsum64(Hrow[lane] * xstwL[lane]);
    if (lane == 0) {
      float xstv = s + xst_b[0];
      xst_cur = xstv;
      float xcv = mrow[0] * xrow[0] + (1.f - mrow[0]) * xstv;
      __hip_atomic_store(&ws[O_XC + dd], xcv, __ATOMIC_RELAXED, SC_AGENT);
      unsigned old = __hip_atomic_fetch_add(cnt, 1u, __ATOMIC_ACQ_REL, SC_AGENT);
      if (old == (unsigned)(NB - 1))
        __hip_atomic_store(flagp, 1u, __ATOMIC_RELEASE, SC_AGENT);
    }
  }

  for (int t = 0; t < TT; ++t) {
    __syncthreads();  // S0: prev-step post-phase writes -> this-step pre reads
    if (tid < HH) {
      hpre[tid] = gpre[0][tid] * hprev[tid];
      Hdec[tid] = gpre[1][tid] * Hrow[tid];
    }
    __syncthreads();  // S1

    // ---- pre-phase (overlaps barrier): gh_ GEMV + u_t GEMV ----
    if (tid < 3 * HH) {
      float a0 = 0.f, a1 = 0.f, a2 = 0.f, a3 = 0.f;
#pragma unroll
      for (int k = 0; k < HH; k += 4) {
        a0 += ws[O_WHHT + (k + 0) * 192 + tid] * hpre[k + 0];
        a1 += ws[O_WHHT + (k + 1) * 192 + tid] * hpre[k + 1];
        a2 += ws[O_WHHT + (k + 2) * 192 + tid] * hpre[k + 2];
        a3 += ws[O_WHHT + (k + 3) * 192 + tid] * hpre[k + 3];
      }
      ghL[tid] = bhhL[tid] + ((a0 + a1) + (a2 + a3));
    } else {
      const int q = lane;
      float acc;
      if (t == 0) {
        acc = wu0b[q];
        DOT64(O_WU0T, h0s, acc);
      } else if (t == 1) {
        acc = wu1b[q];
        DOT64(O_WU1T, h0s, acc);
        DOT64(O_WU1T + 4096, hist[0], acc);
      } else if (t == 2) {
        acc = wub[q];
        DOT64(O_WUT, h0s, acc);
        DOT64(O_WUT + 4096, hist[0], acc);
        DOT64(O_WUT + 8192, hist[1], acc);
      } else {
        const int s0 = (t - 3) % 3, s1 = (t - 2) % 3, s2 = (t - 1) % 3;
        acc = wub[q];
        DOT64(O_WUT, hist[s0], acc);
        DOT64(O_WUT + 4096, hist[s1], acc);
        DOT64(O_WUT + 8192, hist[s2], acc);
      }
      uvec[q] = acc;
    }

    // ---- barrier join: only thread 0 spins, on the broadcast flag ----
    if (tid == 0) {
      const unsigned tgt = (unsigned)(t + 1);
      while (__hip_atomic_load(flagp, __ATOMIC_ACQUIRE, SC_AGENT) < tgt)
        __builtin_amdgcn_s_sleep(1);
    }
    __syncthreads();  // S2

    // ---- post-phase: gi via shfl, gates, h_t (wave0 only) ----
    float hn = 0.f, xcv_reg = 0.f;
    if (wid == 0) {
      float xcv = 0.f;
      if (lane < DD)
        xcv = __hip_atomic_load(&ws[O_XC + t * DD + lane], __ATOMIC_RELAXED,
                                SC_AGENT);
      xcv_reg = xcv;
      float gr = bihL[lane], gz = bihL[64 + lane], gn = bihL[128 + lane];
#pragma unroll
      for (int k = 0; k < DD; ++k) {
        float xk = __shfl(xcv, k, 64);
        gr += wihT_l[k * 192 + lane] * xk;
        gz += wihT_l[k * 192 + 64 + lane] * xk;
        gn += wihT_l[k * 192 + 128 + lane] * xk;
      }
      float r = sigm(gr + ghL[lane]);
      float z = sigm(gz + ghL[64 + lane]);
      float n = tanhf(gn + r * ghL[128 + lane]);
      hn = (1.f - z) * n + z * hpre[lane];
      hnew_l[lane] = hn;
      hist[t % 3][lane] = hn;
      hprev[lane] = hn;
    }
    __syncthreads();  // S3

    // ---- tensor-GRU partial dots (4 waves x 16 k's) ----
    {
      float Hv[16], hv[16];
#pragma unroll
      for (int j = 0; j < 16; ++j) {
        Hv[j] = Hdec[wid * 16 + j];
        hv[j] = hnew_l[wid * 16 + j];
      }
      float pz = 0.f, pr = 0.f, pwh = 0.f, puh = 0.f;
#pragma unroll
      for (int g = 0; g < 4; ++g) {
        const int kg = (wid * 4 + g) * 256 + lane * 4;
        float4 wz = *reinterpret_cast<const float4*>(&wbuf[0][kg]);
        float4 uz = *reinterpret_cast<const float4*>(&wbuf[1][kg]);
        float4 wr = *reinterpret_cast<const float4*>(&wbuf[2][kg]);
        float4 ur = *reinterpret_cast<const float4*>(&wbuf[3][kg]);
        float4 wh = *reinterpret_cast<const float4*>(&wbuf[4][kg]);
        float4 uh = *reinterpret_cast<const float4*>(&wbuf[5][kg]);
        const float a0 = Hv[g * 4 + 0], a1 = Hv[g * 4 + 1];
        const float a2 = Hv[g * 4 + 2], a3 = Hv[g * 4 + 3];
        const float b0 = hv[g * 4 + 0], b1 = hv[g * 4 + 1];
        const float b2 = hv[g * 4 + 2], b3 = hv[g * 4 + 3];
        pz += wz.x * a0 + wz.y * a1 + wz.z * a2 + wz.w * a3;
        pz += uz.x * b0 + uz.y * b1 + uz.z * b2 + uz.w * b3;
        pr += wr.x * a0 + wr.y * a1 + wr.z * a2 + wr.w * a3;
        pr += ur.x * b0 + ur.y * b1 + ur.z * b2 + ur.w * b3;
        pwh += wh.x * a0 + wh.y * a1 + wh.z * a2 + wh.w * a3;
        puh += uh.x * b0 + uh.y * b1 + uh.z * b2 + uh.w * b3;
      }
      part[0][wid][lane] = pz;
      part[1][wid][lane] = pr;
      part[2][wid][lane] = pwh;
      part[3][wid][lane] = puh;
    }
    __syncthreads();  // S4

    // ---- P5: wave0 H-row + epilogue publish + arrive(round t+1);
    //         wave1 softmax-finish(t-1); wave2 gamma prefetch ----
    if (wid == 0) {
      float sz = part[0][0][lane] + part[0][1][lane] + part[0][2][lane] + part[0][3][lane];
      float sr = part[1][0][lane] + part[1][1][lane] + part[1][2][lane] + part[1][3][lane];
      float swh = part[2][0][lane] + part[2][1][lane] + part[2][2][lane] + part[2][3][lane];
      float suh = part[3][0][lane] + part[3][1][lane] + part[3][2][lane] + part[3][3][lane];
      float xc = __shfl(xcv_reg, dd, 64);
      float z = sigm(sz + ux[0][lane] * xc + tb[0][lane]);
      float r = sigm(sr + ux[1][lane] * xc + tb[1][lane]);
      float hh = tanhf(r * swh + ux[2][lane] * xc + suh + tb[2][lane]);
      float Hn = z * Hdec[lane] + (1.f - z) * hh;
      Hrow[lane] = Hn;
      out[t * DD * HH + dd * HH + lane] = Hn;
      float xgt = rsum64(whr0[lane] * hn + whr1[lane] * uvec[lane]);
      float av = rsum64(wrgr[lane] * hn);
      float bv = rsum64(wrsr[lane] * Hn);
      float xsn = rsum64(xstwL[lane] * Hn);
      if (lane == 0) {
        scal2[t & 1][0] = xgt + wh_b[dd];
        scal2[t & 1][1] = xst_cur;
        float s = av + bv;
        __hip_atomic_store(&ws[O_R + t * 66 + dd], av / s, __ATOMIC_RELAXED, SC_AGENT);
        __hip_atomic_store(&ws[O_R + t * 66 + 33 + dd], bv / s, __ATOMIC_RELAXED, SC_AGENT);
        if (t < TT - 1) {
          float xstv = xsn + xst_b[0];
          float xcn = mrow[t + 1] * xrow[t + 1] + (1.f - mrow[t + 1]) * xstv;
          __hip_atomic_store(&ws[O_XC + (t + 1) * DD + dd], xcn, __ATOMIC_RELAXED, SC_AGENT);
          xst_cur = xstv;
        }
        unsigned old = __hip_atomic_fetch_add(cnt, 1u, __ATOMIC_ACQ_REL, SC_AGENT);
        if (old == (unsigned)(NB * (t + 2) - 1))
          __hip_atomic_store(flagp, (unsigned)(t + 2), __ATOMIC_RELEASE, SC_AGENT);
      }
    } else if (wid == 1) {
      if (t > 0) {
        float r1v = -INFINITY, r2v = -INFINITY;
        if (lane < DD) {
          r1v = __hip_atomic_load(&ws[O_R + (t - 1) * 66 + lane], __ATOMIC_RELAXED, SC_AGENT);
          r2v = __hip_atomic_load(&ws[O_R + (t - 1) * 66 + 33 + lane], __ATOMIC_RELAXED, SC_AGENT);
        }
        float m1 = rmax64(r1v), m2 = rmax64(r2v);
        float e1 = (lane < DD) ? expf(r1v - m1) : 0.f;
        float e2 = (lane < DD) ? expf(r2v - m2) : 0.f;
        float s1 = rsum64(e1), s2 = rsum64(e2);
        float r1o = __shfl(r1v, dd, 64);
        float r2o = __shfl(r2v, dd, 64);
        if (lane == 0) {
          float a1 = expf(r1o - m1) / s1;
          float a2 = expf(r2o - m2) / s2;
          out[TT * DD * HH + dd * TT + (t - 1)] =
              a1 * scal2[(t - 1) & 1][0] + a2 * scal2[(t - 1) & 1][1];
        }
      }
    } else if (wid == 2) {
      if (t + 1 < TT) {
        gpre[0][lane] = ws[O_GH + (t + 1) * HH + lane];
        gpre[1][lane] = ws[O_GS + (t + 1) * HH + lane];
      }
    }
  }

  // ---- epilogue: softmax for step TT-1 ----
  if (tid == 0) {
    const unsigned tgt = (unsigned)(TT + 1);
    while (__hip_atomic_load(flagp, __ATOMIC_ACQUIRE, SC_AGENT) < tgt)
      __builtin_amdgcn_s_sleep(1);
  }
  __syncthreads();
  if (wid == 1) {
    float r1v = -INFINITY, r2v = -INFINITY;
    if (lane < DD) {
      r1v = __hip_atomic_load(&ws[O_R + (TT - 1) * 66 + lane], __ATOMIC_RELAXED, SC_AGENT);
      r2v = __hip_atomic_load(&ws[O_R + (TT - 1) * 66 + 33 + lane], __ATOMIC_RELAXED, SC_AGENT);
    }
    float m1 = rmax64(r1v), m2 = rmax64(r2v);
    float e1 = (lane < DD) ? expf(r1v - m1) : 0.f;
    float e2 = (lane < DD) ? expf(r2v - m2) : 0.f;
    float s1 = rsum64(e1), s2 = rsum64(e2);
    float r1o = __shfl(r1v, dd, 64);
    float r2o = __shfl(r2v, dd, 64);
    if (lane == 0) {
      float a1 = expf(r1o - m1) / s1;
      float a2 = expf(r2o - m2) / s2;
      out[TT * DD * HH + dd * TT + (TT - 1)] =
          a1 * scal2[(TT - 1) & 1][0] + a2 * scal2[(TT - 1) & 1][1];
    }
  }
}

extern "C" void kernel_launch(void* const* d_in, const int* in_sizes, int n_in,
                              void* d_out, int out_size, void* d_ws,
                              size_t ws_size, hipStream_t stream) {
  (void)in_sizes; (void)n_in; (void)out_size; (void)ws_size;
  const float* data   = (const float*)d_in[0];
  const float* h0     = (const float*)d_in[1];
  const float* H0     = (const float*)d_in[2];
  const float* gh_w   = (const float*)d_in[3];
  const float* gh_b   = (const float*)d_in[4];
  const float* gst_w  = (const float*)d_in[5];
  const float* gst_b  = (const float*)d_in[6];
  const float* wih    = (const float*)d_in[7];
  const float* whh    = (const float*)d_in[8];
  const float* bih    = (const float*)d_in[9];
  const float* bhh    = (const float*)d_in[10];
  const float* wu0w   = (const float*)d_in[11];
  const float* wu0b   = (const float*)d_in[12];
  const float* wu1w   = (const float*)d_in[13];
  const float* wu1b   = (const float*)d_in[14];
  const float* wuw    = (const float*)d_in[15];
  const float* wub    = (const float*)d_in[16];
  const float* wh_w   = (const float*)d_in[17];
  const float* wh_b   = (const float*)d_in[18];
  const float* xst_w  = (const float*)d_in[19];
  const float* xst_b  = (const float*)d_in[20];
  const float* wrg_w  = (const float*)d_in[21];
  const float* wrs    = (const float*)d_in[22];
  const float* tWz    = (const float*)d_in[23];
  const float* tUzx   = (const float*)d_in[24];
  const float* tUzh   = (const float*)d_in[25];
  const float* tWr    = (const float*)d_in[26];
  const float* tUrx   = (const float*)d_in[27];
  const float* tUrh   = (const float*)d_in[28];
  const float* tWh    = (const float*)d_in[29];
  const float* tUhx   = (const float*)d_in[30];
  const float* tUhh   = (const float*)d_in[31];
  const float* tbz    = (const float*)d_in[32];
  const float* tbr    = (const float*)d_in[33];
  const float* tbh    = (const float*)d_in[34];

  float* ws = (float*)d_ws;
  unsigned* cnt = (unsigned*)(ws + CTR_OFF);
  unsigned* flg = (unsigned*)(ws + FLAG_OFF);

  hipMemsetAsync(cnt, 0, 512, stream);  // covers cnt + flag lines
  gmgru_prep<<<(PREP_N + 255) / 256, 256, 0, stream>>>(
      data, gh_w, gh_b, gst_w, gst_b, wih, whh, wu0w, wu1w, wuw, ws);
  gmgru_main<<<NB, NT, 0, stream>>>(
      data, h0, H0, bih, bhh, wu0b, wu1b, wub, wh_w, wh_b, xst_w, xst_b,
      wrg_w, wrs, tWz, tUzx, tUzh, tWr, tUrx, tUrh, tWh, tUhx, tUhh, tbz, tbr,
      tbh, ws, cnt, flg, (float*)d_out);
}

// Round 4
// 220.467 us; speedup vs baseline: 8.0940x; 8.0940x over previous
//
#include <hip/hip_runtime.h>
#include <math.h>

#define DD 33
#define TT 49
#define HH 64
#define NB 33
#define NT 256

// ws layout (float offsets)
#define O_WIHT  0        // 33*192 wih^T   [k*192+j]
#define O_WHHT  6336     // 64*192 whh^T   [k*192+j]
#define O_GH    18624    // 49*64  gamma_h[t][i]
#define O_GS    21760    // 49*64  gamma_st[t][i]
#define O_WT0   24896    // 33*64   wu0^T . whr1
#define O_WT1   27008    // 33*128  wu1^T . whr1
#define O_WTG   31232    // 33*192  wu^T  . whr1
#define O_CU    37568    // 33*4    whr1 . {wu0b,wu1b,wub,0}
#define O_XC    37700    // 49*33   published x_st_c
#define O_R     39317    // 49*66   published r1(33), r2(33)
#define O_FLAGS 42560    // 64 unsigned flag slots (monotonic)
#define PREP_N  37700

#define SC_AGENT __HIP_MEMORY_SCOPE_AGENT

__device__ __forceinline__ float sigm(float x) { return 1.f / (1.f + expf(-x)); }

__device__ __forceinline__ float rsum64(float v) {
#pragma unroll
  for (int o = 32; o > 0; o >>= 1) v += __shfl_xor(v, o, 64);
  return v;
}
__device__ __forceinline__ float rmax64(float v) {
#pragma unroll
  for (int o = 32; o > 0; o >>= 1) v = fmaxf(v, __shfl_xor(v, o, 64));
  return v;
}

extern "C" __global__ void gmgru_prep(
    const float* __restrict__ data, const float* __restrict__ gh_w,
    const float* __restrict__ gh_b, const float* __restrict__ gst_w,
    const float* __restrict__ gst_b, const float* __restrict__ wih,
    const float* __restrict__ whh, const float* __restrict__ wu0,
    const float* __restrict__ wu0b, const float* __restrict__ wu1,
    const float* __restrict__ wu1b, const float* __restrict__ wu,
    const float* __restrict__ wub, const float* __restrict__ wh_w,
    float* __restrict__ ws) {
  int idx = blockIdx.x * blockDim.x + threadIdx.x;
  if (idx < 6336) {                        // wihT[k*192+j] = wih[j*33+k]
    int k = idx / 192, j = idx % 192;
    ws[O_WIHT + idx] = wih[j * DD + k];
  } else if (idx < 18624) {                // whhT[k*192+j] = whh[j*64+k]
    int r = idx - 6336, k = r / 192, j = r % 192;
    ws[O_WHHT + r] = whh[j * HH + k];
  } else if (idx < 21760) {                // gamma_h[t][i]
    int r = idx - 18624, t = r / 64, i = r % 64;
    float s = gh_b[i];
    for (int d2 = 0; d2 < DD; ++d2)
      s += data[2 * DD * TT + d2 * TT + t] * gh_w[i * DD + d2];
    ws[O_GH + r] = expf(-fmaxf(s, 0.f));
  } else if (idx < 24896) {                // gamma_st[t][i]
    int r = idx - 21760, t = r / 64, i = r % 64;
    float s = gst_b[i];
    for (int d2 = 0; d2 < DD; ++d2)
      s += data[2 * DD * TT + d2 * TT + t] * gst_w[i * DD + d2];
    ws[O_GS + r] = expf(-fmaxf(s, 0.f));
  } else if (idx < 27008) {                // wt0[dd][k] = sum_q wu0[q][k]*whr1[q]
    int r = idx - 24896, dd = r / 64, k = r % 64;
    float s = 0.f;
    for (int q = 0; q < 64; ++q) s += wu0[q * 64 + k] * wh_w[dd * 128 + 64 + q];
    ws[O_WT0 + r] = s;
  } else if (idx < 31232) {                // wt1[dd][k]
    int r = idx - 27008, dd = r / 128, k = r % 128;
    float s = 0.f;
    for (int q = 0; q < 64; ++q) s += wu1[q * 128 + k] * wh_w[dd * 128 + 64 + q];
    ws[O_WT1 + r] = s;
  } else if (idx < 37568) {                // wtg[dd][k]
    int r = idx - 31232, dd = r / 192, k = r % 192;
    float s = 0.f;
    for (int q = 0; q < 64; ++q) s += wu[q * 192 + k] * wh_w[dd * 128 + 64 + q];
    ws[O_WTG + r] = s;
  } else if (idx < PREP_N) {               // cu[dd][v] = whr1 . bias_v
    int r = idx - 37568, dd = r / 4, v = r % 4;
    float s = 0.f;
    if (v < 3) {
      const float* bp = (v == 0) ? wu0b : (v == 1) ? wu1b : wub;
      for (int q = 0; q < 64; ++q) s += bp[q] * wh_w[dd * 128 + 64 + q];
    }
    ws[O_CU + r] = s;
  }
}

extern "C" __global__ void __launch_bounds__(NT)
gmgru_main(const float* __restrict__ data, const float* __restrict__ h0,
           const float* __restrict__ H0, const float* __restrict__ bih,
           const float* __restrict__ bhh, const float* __restrict__ wh_w,
           const float* __restrict__ wh_b, const float* __restrict__ xst_w,
           const float* __restrict__ xst_b, const float* __restrict__ wrg_w,
           const float* __restrict__ wrs, const float* __restrict__ tWz,
           const float* __restrict__ tUzx, const float* __restrict__ tUzh,
           const float* __restrict__ tWr, const float* __restrict__ tUrx,
           const float* __restrict__ tUrh, const float* __restrict__ tWh,
           const float* __restrict__ tUhx, const float* __restrict__ tUhh,
           const float* __restrict__ tbz, const float* __restrict__ tbr,
           const float* __restrict__ tbh, float* __restrict__ ws,
           unsigned* __restrict__ flags, float* __restrict__ out) {
  // LDS: U-half of tensor matrices (float4-packed, transposed), whh^T, wih^T
  __shared__ __attribute__((aligned(16))) float ubuf[3][4096];  // 48 KB
  __shared__ float whhT_l[12288];                               // 48 KB
  __shared__ float wihT_l[6336];                                // 25 KB
  __shared__ float partW[3][4][HH], partU[3][4][HH];            // 6 KB
  __shared__ float ux[3][HH], tbl[3][HH];
  __shared__ float Hrow[HH], Hdec[HH], hpre[HH], hprev[HH], hnew_l[HH], h0s[HH];
  __shared__ float hist[4][HH];   // 4-deep ring: read (t-3)&3 != write t&3
  __shared__ float ghL[3 * HH];
  __shared__ float bihL[3 * HH], bhhL[3 * HH];
  __shared__ float whr0[HH], wtgL[192], wt0L[HH], wt1L[128];
  __shared__ float wrgr[HH], wrsr[HH], xstwL[HH];
  __shared__ float xrow[TT], mrow[TT];
  __shared__ float gpre[2][HH];
  __shared__ float scal2[2][2];  // [t&1][0]=xgt_full, [1]=x_st(t)

  const int tid = threadIdx.x;
  const int dd = blockIdx.x;
  const int wid = tid >> 6;
  const int lane = tid & 63;

  // ---- one-time staging ----
  {
    const float* usrc[3] = {tUzh, tUrh, tUhh};
#pragma unroll 1
    for (int m = 0; m < 3; ++m) {
      const float* s = usrc[m] + dd * 4096;
#pragma unroll
      for (int c = 0; c < 4; ++c) {
        int f = tid * 16 + c * 4;  // source flat idx (i*64+k), k%4==0
        float4 v = *reinterpret_cast<const float4*>(s + f);
        int i = f >> 6, k = f & 63;
        *reinterpret_cast<float4*>(&ubuf[m][(k >> 2) * 256 + i * 4]) = v;
      }
    }
  }
  for (int i = tid; i < 12288; i += NT) whhT_l[i] = ws[O_WHHT + i];
  for (int i = tid; i < 6336; i += NT) wihT_l[i] = ws[O_WIHT + i];
  if (tid < 192) {
    bihL[tid] = bih[tid];
    bhhL[tid] = bhh[tid];
    wtgL[tid] = ws[O_WTG + dd * 192 + tid];
  }
  if (tid < 128) wt1L[tid] = ws[O_WT1 + dd * 128 + tid];
  if (tid < HH) {
    ux[0][tid] = tUzx[dd * HH + tid];
    ux[1][tid] = tUrx[dd * HH + tid];
    ux[2][tid] = tUhx[dd * HH + tid];
    tbl[0][tid] = tbz[tid];
    tbl[1][tid] = tbr[tid];
    tbl[2][tid] = tbh[tid];
    Hrow[tid] = H0[dd * HH + tid];
    float h0v = h0[tid];
    h0s[tid] = h0v;
    hprev[tid] = h0v;
    whr0[tid] = wh_w[dd * 128 + tid];
    wt0L[tid] = ws[O_WT0 + dd * 64 + tid];
    wrgr[tid] = wrg_w[dd * HH + tid];
    wrsr[tid] = wrs[tid];
    xstwL[tid] = xst_w[tid];
    gpre[0][tid] = ws[O_GH + tid];
    gpre[1][tid] = ws[O_GS + tid];
  }
  if (tid < TT) {
    xrow[tid] = data[dd * TT + tid];
    mrow[tid] = data[DD * TT + dd * TT + tid];
  }
  const float whb_r = wh_b[dd];
  const float xstb_r = xst_b[0];
  const float cu0_r = ws[O_CU + dd * 4 + 0];
  const float cu1_r = ws[O_CU + dd * 4 + 1];
  const float cu2_r = ws[O_CU + dd * 4 + 2];
  __syncthreads();

  float xst_cur = 0.f;  // wave0 lane0
  // ---- prologue: publish xc(0), flag=1 ----
  if (wid == 0) {
    float s = rsum64(Hrow[lane] * xstwL[lane]);
    if (lane == 0) {
      float xstv = s + xstb_r;
      xst_cur = xstv;
      float xcv = mrow[0] * xrow[0] + (1.f - mrow[0]) * xstv;
      __hip_atomic_store(&ws[O_XC + dd], xcv, __ATOMIC_RELAXED, SC_AGENT);
      asm volatile("s_waitcnt vmcnt(0)" ::: "memory");
      __hip_atomic_store(&flags[dd], 1u, __ATOMIC_RELAXED, SC_AGENT);
    }
  }

  for (int t = 0; t < TT; ++t) {
    __syncthreads();  // S0
    if (tid < HH) {
      hpre[tid] = gpre[0][tid] * hprev[tid];
      Hdec[tid] = gpre[1][tid] * Hrow[tid];
    }
    __syncthreads();  // S1

    // ---- pre-phase (overlaps barrier): W-half partials from GLOBAL ----
    {
      float Hv[16];
#pragma unroll
      for (int j = 0; j < 16; ++j) Hv[j] = Hdec[wid * 16 + j];
      float pw0 = 0.f, pw1 = 0.f, pw2 = 0.f;
      const int base = dd * 4096 + lane * 64 + wid * 16;
#pragma unroll
      for (int g = 0; g < 4; ++g) {
        float4 a = *reinterpret_cast<const float4*>(tWz + base + g * 4);
        float4 b = *reinterpret_cast<const float4*>(tWr + base + g * 4);
        float4 c = *reinterpret_cast<const float4*>(tWh + base + g * 4);
        const float h0v = Hv[g * 4 + 0], h1v = Hv[g * 4 + 1];
        const float h2v = Hv[g * 4 + 2], h3v = Hv[g * 4 + 3];
        pw0 += a.x * h0v + a.y * h1v + a.z * h2v + a.w * h3v;
        pw1 += b.x * h0v + b.y * h1v + b.z * h2v + b.w * h3v;
        pw2 += c.x * h0v + c.y * h1v + c.z * h2v + c.w * h3v;
      }
      partW[0][wid][lane] = pw0;
      partW[1][wid][lane] = pw1;
      partW[2][wid][lane] = pw2;
    }
    // ---- pre-phase: gh_ GEMV from LDS (threads 0..191) ----
    if (tid < 3 * HH) {
      float a0 = 0.f, a1 = 0.f, a2 = 0.f, a3 = 0.f;
#pragma unroll
      for (int k = 0; k < HH; k += 4) {
        a0 += whhT_l[(k + 0) * 192 + tid] * hpre[k + 0];
        a1 += whhT_l[(k + 1) * 192 + tid] * hpre[k + 1];
        a2 += whhT_l[(k + 2) * 192 + tid] * hpre[k + 2];
        a3 += whhT_l[(k + 3) * 192 + tid] * hpre[k + 3];
      }
      ghL[tid] = bhhL[tid] + ((a0 + a1) + (a2 + a3));
    }

    // ---- wave0: spin (relaxed, slot-per-block), then GRU gates ----
    float hn = 0.f, xcv_reg = 0.f;
    if (wid == 0) {
      const unsigned tgt = (unsigned)(t + 1);
      while (true) {
        unsigned v = (lane < NB)
            ? __hip_atomic_load(&flags[lane], __ATOMIC_RELAXED, SC_AGENT)
            : 0xFFFFFFFFu;
        if (__all((int)(v >= tgt))) break;
        __builtin_amdgcn_s_sleep(1);
      }
      asm volatile("" ::: "memory");  // no load hoisting above the spin
      float xcv = 0.f;
      if (lane < DD)
        xcv = __hip_atomic_load(&ws[O_XC + t * DD + lane], __ATOMIC_RELAXED,
                                SC_AGENT);
      xcv_reg = xcv;
      float gr = bihL[lane], gz = bihL[64 + lane], gn = bihL[128 + lane];
      for (int k = 0; k < DD; ++k) {
        float xk = __shfl(xcv, k, 64);
        gr += wihT_l[k * 192 + lane] * xk;
        gz += wihT_l[k * 192 + 64 + lane] * xk;
        gn += wihT_l[k * 192 + 128 + lane] * xk;
      }
      float r = sigm(gr + ghL[lane]);
      float z = sigm(gz + ghL[64 + lane]);
      float n = tanhf(gn + r * ghL[128 + lane]);
      hn = (1.f - z) * n + z * hpre[lane];
      hnew_l[lane] = hn;
      hist[t & 3][lane] = hn;
      hprev[lane] = hn;
    }
    __syncthreads();  // S3

    // ---- U-half partials from LDS (all waves) ----
    {
      float hv[16];
#pragma unroll
      for (int j = 0; j < 16; ++j) hv[j] = hnew_l[wid * 16 + j];
      float pu0 = 0.f, pu1 = 0.f, pu2 = 0.f;
#pragma unroll
      for (int g = 0; g < 4; ++g) {
        const int kg = (wid * 4 + g) * 256 + lane * 4;
        float4 a = *reinterpret_cast<const float4*>(&ubuf[0][kg]);
        float4 b = *reinterpret_cast<const float4*>(&ubuf[1][kg]);
        float4 c = *reinterpret_cast<const float4*>(&ubuf[2][kg]);
        const float h0v = hv[g * 4 + 0], h1v = hv[g * 4 + 1];
        const float h2v = hv[g * 4 + 2], h3v = hv[g * 4 + 3];
        pu0 += a.x * h0v + a.y * h1v + a.z * h2v + a.w * h3v;
        pu1 += b.x * h0v + b.y * h1v + b.z * h2v + b.w * h3v;
        pu2 += c.x * h0v + c.y * h1v + c.z * h2v + c.w * h3v;
      }
      partU[0][wid][lane] = pu0;
      partU[1][wid][lane] = pu1;
      partU[2][wid][lane] = pu2;
    }
    __syncthreads();  // S4

    // ---- P5: wave0 combine -> H row, publish; wave1 softmax(t-1);
    //          wave2 gamma prefetch ----
    if (wid == 0) {
      float sz = partW[0][0][lane] + partW[0][1][lane] + partW[0][2][lane] +
                 partW[0][3][lane] + partU[0][0][lane] + partU[0][1][lane] +
                 partU[0][2][lane] + partU[0][3][lane];
      float sr = partW[1][0][lane] + partW[1][1][lane] + partW[1][2][lane] +
                 partW[1][3][lane] + partU[1][0][lane] + partU[1][1][lane] +
                 partU[1][2][lane] + partU[1][3][lane];
      float swh = partW[2][0][lane] + partW[2][1][lane] + partW[2][2][lane] +
                  partW[2][3][lane];
      float suh = partU[2][0][lane] + partU[2][1][lane] + partU[2][2][lane] +
                  partU[2][3][lane];
      float xc = __shfl(xcv_reg, dd, 64);
      float z = sigm(sz + ux[0][lane] * xc + tbl[0][lane]);
      float r = sigm(sr + ux[1][lane] * xc + tbl[1][lane]);
      float hh = tanhf(r * swh + ux[2][lane] * xc + suh + tbl[2][lane]);
      float Hn = z * Hdec[lane] + (1.f - z) * hh;
      Hrow[lane] = Hn;
      out[t * DD * HH + dd * HH + lane] = Hn;
      // xgt via precomputed w~ ; a, b, x_st(t+1)
      float xg = whr0[lane] * hn;
      if (t == 0) {
        xg += wt0L[lane] * h0s[lane];
      } else if (t == 1) {
        xg += wt1L[lane] * h0s[lane] + wt1L[64 + lane] * hist[0][lane];
      } else if (t == 2) {
        xg += wtgL[lane] * h0s[lane] + wtgL[64 + lane] * hist[0][lane] +
              wtgL[128 + lane] * hist[1][lane];
      } else {
        const int s0 = (t - 3) & 3, s1 = (t - 2) & 3, s2 = (t - 1) & 3;
        xg += wtgL[lane] * hist[s0][lane] + wtgL[64 + lane] * hist[s1][lane] +
              wtgL[128 + lane] * hist[s2][lane];
      }
      float xgt = rsum64(xg);
      float av = rsum64(wrgr[lane] * hn);
      float bv = rsum64(wrsr[lane] * Hn);
      float xsn = rsum64(xstwL[lane] * Hn);
      if (lane == 0) {
        float cu = (t == 0) ? cu0_r : (t == 1) ? cu1_r : cu2_r;
        scal2[t & 1][0] = xgt + whb_r + cu;
        scal2[t & 1][1] = xst_cur;
        float s = av + bv;
        __hip_atomic_store(&ws[O_R + t * 66 + dd], av / s, __ATOMIC_RELAXED,
                           SC_AGENT);
        __hip_atomic_store(&ws[O_R + t * 66 + 33 + dd], bv / s,
                           __ATOMIC_RELAXED, SC_AGENT);
        if (t < TT - 1) {
          float xstv = xsn + xstb_r;
          float xcn = mrow[t + 1] * xrow[t + 1] + (1.f - mrow[t + 1]) * xstv;
          __hip_atomic_store(&ws[O_XC + (t + 1) * DD + dd], xcn,
                             __ATOMIC_RELAXED, SC_AGENT);
          xst_cur = xstv;
        }
        asm volatile("s_waitcnt vmcnt(0)" ::: "memory");
        __hip_atomic_store(&flags[dd], (unsigned)(t + 2), __ATOMIC_RELAXED,
                           SC_AGENT);
      }
    } else if (wid == 1) {
      if (t > 0) {
        float r1v = -INFINITY, r2v = -INFINITY;
        if (lane < DD) {
          r1v = __hip_atomic_load(&ws[O_R + (t - 1) * 66 + lane],
                                  __ATOMIC_RELAXED, SC_AGENT);
          r2v = __hip_atomic_load(&ws[O_R + (t - 1) * 66 + 33 + lane],
                                  __ATOMIC_RELAXED, SC_AGENT);
        }
        float m1 = rmax64(r1v), m2 = rmax64(r2v);
        float e1 = (lane < DD) ? expf(r1v - m1) : 0.f;
        float e2 = (lane < DD) ? expf(r2v - m2) : 0.f;
        float s1 = rsum64(e1), s2 = rsum64(e2);
        float r1o = __shfl(r1v, dd, 64);
        float r2o = __shfl(r2v, dd, 64);
        if (lane == 0) {
          float a1 = expf(r1o - m1) / s1;
          float a2 = expf(r2o - m2) / s2;
          out[TT * DD * HH + dd * TT + (t - 1)] =
              a1 * scal2[(t - 1) & 1][0] + a2 * scal2[(t - 1) & 1][1];
        }
      }
    } else if (wid == 2) {
      if (t + 1 < TT) {
        gpre[0][lane] = ws[O_GH + (t + 1) * HH + lane];
        gpre[1][lane] = ws[O_GS + (t + 1) * HH + lane];
      }
    }
  }

  // ---- epilogue: softmax for step TT-1 ----
  if (wid == 0) {
    const unsigned tgt = (unsigned)(TT + 1);
    while (true) {
      unsigned v = (lane < NB)
          ? __hip_atomic_load(&flags[lane], __ATOMIC_RELAXED, SC_AGENT)
          : 0xFFFFFFFFu;
      if (__all((int)(v >= tgt))) break;
      __builtin_amdgcn_s_sleep(1);
    }
    asm volatile("" ::: "memory");
  }
  __syncthreads();
  if (wid == 1) {
    float r1v = -INFINITY, r2v = -INFINITY;
    if (lane < DD) {
      r1v = __hip_atomic_load(&ws[O_R + (TT - 1) * 66 + lane], __ATOMIC_RELAXED,
                              SC_AGENT);
      r2v = __hip_atomic_load(&ws[O_R + (TT - 1) * 66 + 33 + lane],
                              __ATOMIC_RELAXED, SC_AGENT);
    }
    float m1 = rmax64(r1v), m2 = rmax64(r2v);
    float e1 = (lane < DD) ? expf(r1v - m1) : 0.f;
    float e2 = (lane < DD) ? expf(r2v - m2) : 0.f;
    float s1 = rsum64(e1), s2 = rsum64(e2);
    float r1o = __shfl(r1v, dd, 64);
    float r2o = __shfl(r2v, dd, 64);
    if (lane == 0) {
      float a1 = expf(r1o - m1) / s1;
      float a2 = expf(r2o - m2) / s2;
      out[TT * DD * HH + dd * TT + (TT - 1)] =
          a1 * scal2[(TT - 1) & 1][0] + a2 * scal2[(TT - 1) & 1][1];
    }
  }
}

extern "C" void kernel_launch(void* const* d_in, const int* in_sizes, int n_in,
                              void* d_out, int out_size, void* d_ws,
                              size_t ws_size, hipStream_t stream) {
  (void)in_sizes; (void)n_in; (void)out_size; (void)ws_size;
  const float* data   = (const float*)d_in[0];
  const float* h0     = (const float*)d_in[1];
  const float* H0     = (const float*)d_in[2];
  const float* gh_w   = (const float*)d_in[3];
  const float* gh_b   = (const float*)d_in[4];
  const float* gst_w  = (const float*)d_in[5];
  const float* gst_b  = (const float*)d_in[6];
  const float* wih    = (const float*)d_in[7];
  const float* whh    = (const float*)d_in[8];
  const float* bih    = (const float*)d_in[9];
  const float* bhh    = (const float*)d_in[10];
  const float* wu0w   = (const float*)d_in[11];
  const float* wu0b   = (const float*)d_in[12];
  const float* wu1w   = (const float*)d_in[13];
  const float* wu1b   = (const float*)d_in[14];
  const float* wuw    = (const float*)d_in[15];
  const float* wub    = (const float*)d_in[16];
  const float* wh_w   = (const float*)d_in[17];
  const float* wh_b   = (const float*)d_in[18];
  const float* xst_w  = (const float*)d_in[19];
  const float* xst_b  = (const float*)d_in[20];
  const float* wrg_w  = (const float*)d_in[21];
  const float* wrs    = (const float*)d_in[22];
  const float* tWz    = (const float*)d_in[23];
  const float* tUzx   = (const float*)d_in[24];
  const float* tUzh   = (const float*)d_in[25];
  const float* tWr    = (const float*)d_in[26];
  const float* tUrx   = (const float*)d_in[27];
  const float* tUrh   = (const float*)d_in[28];
  const float* tWh    = (const float*)d_in[29];
  const float* tUhx   = (const float*)d_in[30];
  const float* tUhh   = (const float*)d_in[31];
  const float* tbz    = (const float*)d_in[32];
  const float* tbr    = (const float*)d_in[33];
  const float* tbh    = (const float*)d_in[34];

  float* ws = (float*)d_ws;
  unsigned* flags = (unsigned*)(ws + O_FLAGS);

  hipMemsetAsync(flags, 0, 64 * sizeof(unsigned), stream);
  gmgru_prep<<<(PREP_N + 255) / 256, 256, 0, stream>>>(
      data, gh_w, gh_b, gst_w, gst_b, wih, whh, wu0w, wu0b, wu1w, wu1b, wuw,
      wub, wh_w, ws);
  gmgru_main<<<NB, NT, 0, stream>>>(
      data, h0, H0, bih, bhh, wh_w, wh_b, xst_w, xst_b, wrg_w, wrs, tWz, tUzx,
      tUzh, tWr, tUrx, tUrh, tWh, tUhx, tUhh, tbz, tbr, tbh, ws, flags,
      (float*)d_out);
}